// Round 1
// baseline (1244.004 us; speedup 1.0000x reference)
//
#include <hip/hip_runtime.h>
#include <cstddef>
#include <cstdint>

typedef _Float16 f16;
typedef __attribute__((ext_vector_type(4))) _Float16 half4;
typedef __attribute__((ext_vector_type(8))) _Float16 half8;
typedef __attribute__((ext_vector_type(4))) float floatx4;

#define TSEQ 2048
#define DMODEL 2048
#define LDQKV 3072
#define NHEADS 16
#define NKVH 4
#define HD 128
#define INTERDIM 5632
#define LDGU 11264

// ---------------- fp32 -> fp16 cast ----------------
__global__ __launch_bounds__(256) void cast_kernel(const float* __restrict__ in,
                                                   f16* __restrict__ out, int n4) {
    int i = blockIdx.x * 256 + threadIdx.x;
    if (i >= n4) return;
    float4 v = ((const float4*)in)[i];
    half4 o;
    o.x = (f16)v.x; o.y = (f16)v.y; o.z = (f16)v.z; o.w = (f16)v.w;
    ((half4*)out)[i] = o;
}

// ---------------- RMSNorm (fp32 in, fp16 out), row = 2048 ----------------
__global__ __launch_bounds__(256) void rmsnorm_kernel(const float* __restrict__ x,
                                                      const float* __restrict__ w,
                                                      f16* __restrict__ out) {
    int row = blockIdx.x;
    const float* xr = x + (size_t)row * DMODEL;
    int base = threadIdx.x * 8;
    float4 a = *(const float4*)(xr + base);
    float4 b = *(const float4*)(xr + base + 4);
    float ss = a.x*a.x + a.y*a.y + a.z*a.z + a.w*a.w
             + b.x*b.x + b.y*b.y + b.z*b.z + b.w*b.w;
#pragma unroll
    for (int off = 32; off >= 1; off >>= 1) ss += __shfl_xor(ss, off, 64);
    __shared__ float part[4];
    if ((threadIdx.x & 63) == 0) part[threadIdx.x >> 6] = ss;
    __syncthreads();
    float tot = part[0] + part[1] + part[2] + part[3];
    float inv = rsqrtf(tot * (1.0f / DMODEL) + 1e-6f);
    const float* wr = w + base;
    half8 o;
    o[0] = (f16)(a.x * inv * wr[0]);
    o[1] = (f16)(a.y * inv * wr[1]);
    o[2] = (f16)(a.z * inv * wr[2]);
    o[3] = (f16)(a.w * inv * wr[3]);
    o[4] = (f16)(b.x * inv * wr[4]);
    o[5] = (f16)(b.y * inv * wr[5]);
    o[6] = (f16)(b.z * inv * wr[6]);
    o[7] = (f16)(b.w * inv * wr[7]);
    *(half8*)(out + (size_t)row * DMODEL + base) = o;
}

// ---------------- GEMM: C[M,N] = A[M,K] @ B[N,K]^T (both row-major, fp16) ----
// 128x128 tile, BK=32, 256 threads (4 waves, 2x2), mfma_f32_16x16x32_f16.
// outmode: Cf!=nullptr -> fp32 store with residual add; else fp16 store.
__device__ __forceinline__ int swz(int r, int c) {
    return c ^ (r & 3) ^ ((r >> 2) & 3);
}

__global__ __launch_bounds__(256) void gemm_bt(const f16* __restrict__ A, int lda,
                                               const f16* __restrict__ B, int ldb,
                                               f16* __restrict__ Ch, float* __restrict__ Cf,
                                               const float* __restrict__ res,
                                               int ldc, int K) {
    const int col0 = blockIdx.x * 128, row0 = blockIdx.y * 128;
    const int t = threadIdx.x;
    const int w = t >> 6, lane = t & 63, cl = lane & 15, quad = lane >> 4;
    const int wm = (w >> 1) * 64, wn = (w & 1) * 64;
    __shared__ __align__(16) f16 As[128 * 32];
    __shared__ __align__(16) f16 Bs[128 * 32];

    const int r0 = t >> 2, cc = t & 3;
    const int r1 = r0 + 64;
    const f16* gA0 = A + (size_t)(row0 + r0) * lda + cc * 8;
    const f16* gA1 = A + (size_t)(row0 + r1) * lda + cc * 8;
    const f16* gB0 = B + (size_t)(col0 + r0) * ldb + cc * 8;
    const f16* gB1 = B + (size_t)(col0 + r1) * ldb + cc * 8;
    f16* sA0 = &As[r0 * 32 + swz(r0, cc) * 8];
    f16* sA1 = &As[r1 * 32 + swz(r1, cc) * 8];
    f16* sB0 = &Bs[r0 * 32 + swz(r0, cc) * 8];
    f16* sB1 = &Bs[r1 * 32 + swz(r1, cc) * 8];

    const f16* fa[4];
    const f16* fb[4];
#pragma unroll
    for (int mt = 0; mt < 4; ++mt) {
        int rr = wm + mt * 16 + cl;
        fa[mt] = &As[rr * 32 + swz(rr, quad) * 8];
        rr = wn + mt * 16 + cl;
        fb[mt] = &Bs[rr * 32 + swz(rr, quad) * 8];
    }

    const floatx4 fzero = {0.f, 0.f, 0.f, 0.f};
    floatx4 acc[4][4];
#pragma unroll
    for (int mt = 0; mt < 4; ++mt)
#pragma unroll
        for (int nt = 0; nt < 4; ++nt) acc[mt][nt] = fzero;

    int4 ra0 = *(const int4*)gA0, ra1 = *(const int4*)gA1;
    int4 rb0 = *(const int4*)gB0, rb1 = *(const int4*)gB1;

    for (int k0 = 0; k0 < K; k0 += 32) {
        __syncthreads();
        *(int4*)sA0 = ra0; *(int4*)sA1 = ra1;
        *(int4*)sB0 = rb0; *(int4*)sB1 = rb1;
        __syncthreads();
        int kn = k0 + 32;
        if (kn < K) {
            ra0 = *(const int4*)(gA0 + kn);
            ra1 = *(const int4*)(gA1 + kn);
            rb0 = *(const int4*)(gB0 + kn);
            rb1 = *(const int4*)(gB1 + kn);
        }
        half8 av[4], bv[4];
#pragma unroll
        for (int mt = 0; mt < 4; ++mt) av[mt] = *(const half8*)fa[mt];
#pragma unroll
        for (int nt = 0; nt < 4; ++nt) bv[nt] = *(const half8*)fb[nt];
#pragma unroll
        for (int mt = 0; mt < 4; ++mt)
#pragma unroll
            for (int nt = 0; nt < 4; ++nt)
                acc[mt][nt] = __builtin_amdgcn_mfma_f32_16x16x32_f16(av[mt], bv[nt],
                                                                     acc[mt][nt], 0, 0, 0);
    }

#pragma unroll
    for (int mt = 0; mt < 4; ++mt)
#pragma unroll
        for (int nt = 0; nt < 4; ++nt)
#pragma unroll
            for (int r = 0; r < 4; ++r) {
                int grow = row0 + wm + mt * 16 + quad * 4 + r;
                int gcol = col0 + wn + nt * 16 + cl;
                size_t idx = (size_t)grow * ldc + gcol;
                float v = acc[mt][nt][r];
                if (Cf) Cf[idx] = res[idx] + v;
                else    Ch[idx] = (f16)v;
            }
}

// ---------------- RoPE (in-place on q and k columns of qkv) ----------------
__global__ __launch_bounds__(256) void rope_kernel(f16* __restrict__ qkv) {
    int idx = blockIdx.x * 256 + threadIdx.x;  // 4096 * 1280
    int row = idx / 1280;
    int p = idx - row * 1280;
    int t = row & (TSEQ - 1);
    int colbase, i;
    if (p < 1024) { colbase = (p >> 6) * 128; i = p & 63; }
    else { int pp = p - 1024; colbase = 2048 + (pp >> 6) * 128; i = pp & 63; }
    float inv = expf((float)i * -0.14391156831f);  // ln(10000)/64
    float ang = (float)t * inv;
    float s, c;
    sincosf(ang, &s, &c);
    size_t base = (size_t)row * LDQKV + colbase;
    float x1 = (float)qkv[base + i];
    float x2 = (float)qkv[base + 64 + i];
    qkv[base + i]      = (f16)(x1 * c - x2 * s);
    qkv[base + 64 + i] = (f16)(x2 * c + x1 * s);
}

// ---------------- transpose V: (b,t,kvh,d) -> vt[(b,kvh,d), t] ----------------
__global__ __launch_bounds__(256) void transpose_v(const f16* __restrict__ qkv,
                                                   f16* __restrict__ vt) {
    int z = blockIdx.z;  // b*4 + kvh
    int b = z >> 2, kvh = z & 3;
    int t0 = blockIdx.x * 32, d0 = blockIdx.y * 32;
    __shared__ f16 tile[32][33];
    const f16* src = qkv + (size_t)(b * TSEQ + t0) * LDQKV + 2560 + kvh * HD + d0;
    for (int i = threadIdx.y; i < 32; i += 8)
        tile[i][threadIdx.x] = src[(size_t)i * LDQKV + threadIdx.x];
    __syncthreads();
    f16* dst = vt + (size_t)(z * HD + d0) * TSEQ + t0;
    for (int i = threadIdx.y; i < 32; i += 8)
        dst[(size_t)i * TSEQ + threadIdx.x] = tile[threadIdx.x][i];
}

// ---------------- flash attention: 1 wave/block, 16 q-rows, 32-k chunks -----
__global__ __launch_bounds__(64) void flash_attn(const f16* __restrict__ qkv,
                                                 const f16* __restrict__ vt,
                                                 f16* __restrict__ out) {
    int q0 = blockIdx.x * 16;
    int h = blockIdx.y, b = blockIdx.z;
    int lane = threadIdx.x, cl = lane & 15, quad = lane >> 4;
    int kvh = h >> 2;
    const f16* Q  = qkv + (size_t)b * TSEQ * LDQKV + h * HD;
    const f16* Kp = qkv + (size_t)b * TSEQ * LDQKV + DMODEL + kvh * HD;
    const f16* Vt = vt + (size_t)(b * NKVH + kvh) * HD * TSEQ;

    half8 qf[4];
#pragma unroll
    for (int ks = 0; ks < 4; ++ks)
        qf[ks] = *(const half8*)(Q + (size_t)(q0 + cl) * LDQKV + ks * 32 + quad * 8);

    float m_r[4] = {-1e30f, -1e30f, -1e30f, -1e30f};
    float l_r[4] = {0.f, 0.f, 0.f, 0.f};
    const floatx4 fzero = {0.f, 0.f, 0.f, 0.f};
    floatx4 o[8];
#pragma unroll
    for (int nt = 0; nt < 8; ++nt) o[nt] = fzero;

    __shared__ __align__(16) f16 P[16 * 32];
    const float scale = 0.088388347648318447f;  // 1/sqrt(128)
    int nsteps = (q0 >> 5) + 1;

    for (int si = 0; si < nsteps; ++si) {
        int kb = si * 32;
        floatx4 c0 = fzero, c1 = fzero;
        const f16* K0 = Kp + (size_t)(kb + cl) * LDQKV + quad * 8;
        const f16* K1 = K0 + (size_t)16 * LDQKV;
#pragma unroll
        for (int ks = 0; ks < 4; ++ks) {
            c0 = __builtin_amdgcn_mfma_f32_16x16x32_f16(qf[ks], *(const half8*)(K0 + ks * 32), c0, 0, 0, 0);
            c1 = __builtin_amdgcn_mfma_f32_16x16x32_f16(qf[ks], *(const half8*)(K1 + ks * 32), c1, 0, 0, 0);
        }
        float alpha[4], ps0[4], ps1[4];
#pragma unroll
        for (int r = 0; r < 4; ++r) {
            int qpos = q0 + quad * 4 + r;
            float s0 = c0[r] * scale; if (kb + cl > qpos)      s0 = -1e30f;
            float s1 = c1[r] * scale; if (kb + 16 + cl > qpos) s1 = -1e30f;
            float mx = fmaxf(s0, s1);
#pragma unroll
            for (int off = 1; off < 16; off <<= 1) mx = fmaxf(mx, __shfl_xor(mx, off, 64));
            float mnew = fmaxf(m_r[r], mx);
            alpha[r] = __expf(m_r[r] - mnew);
            float p0 = __expf(s0 - mnew), p1 = __expf(s1 - mnew);
            float rs = p0 + p1;
#pragma unroll
            for (int off = 1; off < 16; off <<= 1) rs += __shfl_xor(rs, off, 64);
            l_r[r] = l_r[r] * alpha[r] + rs;
            m_r[r] = mnew;
            ps0[r] = p0; ps1[r] = p1;
        }
#pragma unroll
        for (int nt = 0; nt < 8; ++nt) {
            floatx4 tv = o[nt];
            tv[0] *= alpha[0]; tv[1] *= alpha[1]; tv[2] *= alpha[2]; tv[3] *= alpha[3];
            o[nt] = tv;
        }
        __syncthreads();  // prior P reads done before overwrite
#pragma unroll
        for (int r = 0; r < 4; ++r) {
            P[(quad * 4 + r) * 32 + cl]      = (f16)ps0[r];
            P[(quad * 4 + r) * 32 + 16 + cl] = (f16)ps1[r];
        }
        __syncthreads();
        half8 pf = *(const half8*)&P[cl * 32 + quad * 8];
#pragma unroll
        for (int nt = 0; nt < 8; ++nt) {
            half8 vv = *(const half8*)(Vt + (size_t)(nt * 16 + cl) * TSEQ + kb + quad * 8);
            o[nt] = __builtin_amdgcn_mfma_f32_16x16x32_f16(pf, vv, o[nt], 0, 0, 0);
        }
    }

    f16* Op = out + (size_t)(b * TSEQ + q0) * DMODEL + h * HD;
#pragma unroll
    for (int nt = 0; nt < 8; ++nt)
#pragma unroll
        for (int r = 0; r < 4; ++r)
            Op[(size_t)(quad * 4 + r) * DMODEL + nt * 16 + cl] = (f16)(o[nt][r] / l_r[r]);
}

// ---------------- SwiGLU: gu[:, :5632] = silu(gate) * up (in place) ---------
__global__ __launch_bounds__(256) void silu_mul(f16* __restrict__ gu) {
    int idx = blockIdx.x * 256 + threadIdx.x;  // 4096 * 704
    int row = idx / 704;
    int j = (idx - row * 704) * 8;
    size_t base = (size_t)row * LDGU;
    half8 g = *(half8*)(gu + base + j);
    half8 u = *(half8*)(gu + base + INTERDIM + j);
    half8 o;
#pragma unroll
    for (int e = 0; e < 8; ++e) {
        float gv = (float)g[e], uv = (float)u[e];
        float sg = gv / (1.f + __expf(-gv));
        o[e] = (f16)(sg * uv);
    }
    *(half8*)(gu + base + j) = o;
}

extern "C" void kernel_launch(void* const* d_in, const int* in_sizes, int n_in,
                              void* d_out, int out_size, void* d_ws, size_t ws_size,
                              hipStream_t stream) {
    const float* x   = (const float*)d_in[0];
    const float* ln1 = (const float*)d_in[1];
    const float* ln2 = (const float*)d_in[2];
    const float* wq  = (const float*)d_in[3];
    const float* wk  = (const float*)d_in[4];
    const float* wv  = (const float*)d_in[5];
    const float* wo  = (const float*)d_in[6];
    const float* wg  = (const float*)d_in[7];
    const float* wu  = (const float*)d_in[8];
    const float* wd  = (const float*)d_in[9];
    float* out = (float*)d_out;

    char* p = (char*)d_ws;
    f16* wqkv_h = (f16*)p; p += (size_t)3072 * 2048 * 2;
    f16* wo_h   = (f16*)p; p += (size_t)2048 * 2048 * 2;
    f16* wgu_h  = (f16*)p; p += (size_t)11264 * 2048 * 2;
    f16* wd_h   = (f16*)p; p += (size_t)2048 * 5632 * 2;
    f16* h_h    = (f16*)p; p += (size_t)4096 * 2048 * 2;  // later reused as attn-out
    f16* qkv_h  = (f16*)p; p += (size_t)4096 * 3072 * 2;  // later reused as h2
    f16* vt_h   = (f16*)p; p += (size_t)8 * 128 * 2048 * 2;
    f16* gu_h   = (f16*)p;                                 // 4096*11264*2

    auto cast = [&](const float* src, f16* dst, size_t n) {
        int n4 = (int)(n / 4);
        cast_kernel<<<(n4 + 255) / 256, 256, 0, stream>>>(src, dst, n4);
    };
    cast(wq, wqkv_h,                       (size_t)2048 * 2048);
    cast(wk, wqkv_h + (size_t)2048 * 2048, (size_t)512 * 2048);
    cast(wv, wqkv_h + (size_t)2560 * 2048, (size_t)512 * 2048);
    cast(wo, wo_h,                         (size_t)2048 * 2048);
    cast(wg, wgu_h,                        (size_t)5632 * 2048);
    cast(wu, wgu_h + (size_t)5632 * 2048,  (size_t)5632 * 2048);
    cast(wd, wd_h,                         (size_t)2048 * 5632);

    rmsnorm_kernel<<<4096, 256, 0, stream>>>(x, ln1, h_h);
    // QKV projection (fused N = 2048+512+512 = 3072)
    gemm_bt<<<dim3(24, 32), 256, 0, stream>>>(h_h, 2048, wqkv_h, 2048,
                                              qkv_h, nullptr, nullptr, 3072, 2048);
    rope_kernel<<<20480, 256, 0, stream>>>(qkv_h);
    transpose_v<<<dim3(64, 4, 8), dim3(32, 8), 0, stream>>>(qkv_h, vt_h);
    flash_attn<<<dim3(128, 16, 2), 64, 0, stream>>>(qkv_h, vt_h, h_h);
    // out = x + attn @ wo^T   (fp32 residual into d_out)
    gemm_bt<<<dim3(16, 32), 256, 0, stream>>>(h_h, 2048, wo_h, 2048,
                                              nullptr, out, x, 2048, 2048);
    rmsnorm_kernel<<<4096, 256, 0, stream>>>(out, ln2, qkv_h);  // h2 in qkv buffer
    // gate|up (fused N = 11264)
    gemm_bt<<<dim3(88, 32), 256, 0, stream>>>(qkv_h, 2048, wgu_h, 2048,
                                              gu_h, nullptr, nullptr, 11264, 2048);
    silu_mul<<<11264, 256, 0, stream>>>(gu_h);
    // out += mid @ wd^T
    gemm_bt<<<dim3(16, 32), 256, 0, stream>>>(gu_h, 11264, wd_h, 5632,
                                              nullptr, out, out, 2048, 5632);
}